// Round 16
// baseline (316.707 us; speedup 1.0000x reference)
//
#include <hip/hip_runtime.h>
#include <hip/hip_bf16.h>
#include <stdint.h>

// ---------- helpers ----------
typedef __attribute__((ext_vector_type(8))) short short8v;    // 8 x 16-bit (4 VGPRs)
typedef __attribute__((ext_vector_type(8))) _Float16 half8v;  // 8 x f16
typedef __attribute__((ext_vector_type(4))) float f32x4;

__device__ __forceinline__ unsigned short f2bf(float f) {
  unsigned u = __builtin_bit_cast(unsigned, f);
  unsigned r = 0x7fffu + ((u >> 16) & 1u);          // round-to-nearest-even
  return (unsigned short)((u + r) >> 16);
}
__device__ __forceinline__ float bf2f(unsigned short h) {
  unsigned u = ((unsigned)h) << 16;
  return __builtin_bit_cast(float, u);
}
__device__ __forceinline__ unsigned short f2h(float f) {
  _Float16 h = (_Float16)f;                         // RTNE
  return __builtin_bit_cast(unsigned short, h);
}
__device__ __forceinline__ void gload_lds16(const void* g, void* l) {
  __builtin_amdgcn_global_load_lds(
      (const __attribute__((address_space(1))) void*)g,
      (__attribute__((address_space(3))) void*)l, 16, 0, 0);
}
#define SBAR  __builtin_amdgcn_s_barrier()
#define SCHED __builtin_amdgcn_sched_barrier(0)

// ---------- split / convert kernels ----------
__global__ __launch_bounds__(256) void split_plain(
    const float4* __restrict__ X, ushort4* __restrict__ H, ushort4* __restrict__ L, int n4) {
  int idx = blockIdx.x * 256 + threadIdx.x;
  if (idx >= n4) return;
  float4 v = X[idx];
  ushort4 h, l;
  h.x = f2bf(v.x); l.x = f2bf(v.x - bf2f(h.x));
  h.y = f2bf(v.y); l.y = f2bf(v.y - bf2f(h.y));
  h.z = f2bf(v.z); l.z = f2bf(v.z - bf2f(h.z));
  h.w = f2bf(v.w); l.w = f2bf(v.w - bf2f(h.w));
  H[idx] = h; L[idx] = l;
}

// x: one pass -> bf16 hi/lo + f16 copy
__global__ __launch_bounds__(256) void split_x3(
    const float4* __restrict__ X, ushort4* __restrict__ H, ushort4* __restrict__ L,
    ushort4* __restrict__ F, int n4) {
  int idx = blockIdx.x * 256 + threadIdx.x;
  if (idx >= n4) return;
  float4 v = X[idx];
  ushort4 h, l, f;
  h.x = f2bf(v.x); l.x = f2bf(v.x - bf2f(h.x)); f.x = f2h(v.x);
  h.y = f2bf(v.y); l.y = f2bf(v.y - bf2f(h.y)); f.y = f2h(v.y);
  h.z = f2bf(v.z); l.z = f2bf(v.z - bf2f(h.z)); f.z = f2h(v.z);
  h.w = f2bf(v.w); l.w = f2bf(v.w - bf2f(h.w)); f.w = f2h(v.w);
  H[idx] = h; L[idx] = l; F[idx] = f;
}

template<bool WL>
__global__ __launch_bounds__(256) void split_T(
    const float* __restrict__ W, unsigned short* __restrict__ H,
    unsigned short* __restrict__ L, int Kd, int Nd) {
  __shared__ float tile[32][33];
  const int t = threadIdx.x;
  const int c = t & 31;
  const int r0 = t >> 5;
  const int k0 = blockIdx.y * 32, n0 = blockIdx.x * 32;
#pragma unroll
  for (int i = 0; i < 4; ++i) {
    int r = r0 + i * 8;
    tile[r][c] = W[(size_t)(k0 + r) * Nd + n0 + c];
  }
  __syncthreads();
#pragma unroll
  for (int i = 0; i < 4; ++i) {
    int n = r0 + i * 8;
    float f = tile[c][n];
    unsigned short h = f2bf(f);
    size_t o = (size_t)(n0 + n) * Kd + k0 + c;
    H[o] = h;
    if (WL) L[o] = f2bf(f - bf2f(h));
  }
}

// ---------- M-transpose reduce: Mt[b][a] = split(sum_s Mpart[s][a][b]) ----------
__global__ __launch_bounds__(256) void reduceT_M(
    const float* __restrict__ P, unsigned short* __restrict__ H,
    unsigned short* __restrict__ L, int nsplit) {
  __shared__ float tile[32][33];
  const int t = threadIdx.x;
  const int c = t & 31;
  const int r0 = t >> 5;
  const int a0 = blockIdx.y * 32, b0 = blockIdx.x * 32;
#pragma unroll
  for (int i = 0; i < 4; ++i) {
    int r = r0 + i * 8;
    float s = 0.f;
    for (int sp = 0; sp < nsplit; ++sp)
      s += P[(size_t)sp * 1048576 + (size_t)(a0 + r) * 1024 + b0 + c];
    tile[r][c] = s;
  }
  __syncthreads();
#pragma unroll
  for (int i = 0; i < 4; ++i) {
    int b = r0 + i * 8;
    float f = tile[c][b];                 // = M[a0+c][b0+b]
    unsigned short h = f2bf(f);
    size_t o = (size_t)(b0 + b) * 1024 + a0 + c;   // Mt[b][a]
    H[o] = h;
    L[o] = f2bf(f - bf2f(h));
  }
}

// ---------- reduce -> f16 ----------
__global__ __launch_bounds__(256) void reduce_f16(
    const float4* __restrict__ P, ushort4* __restrict__ H,
    int n4, int nsplit, int stride4) {
  int idx = blockIdx.x * 256 + threadIdx.x;
  if (idx >= n4) return;
  float4 s = P[idx];
  for (int sp = 1; sp < nsplit; ++sp) {
    float4 v = P[(size_t)sp * stride4 + idx];
    s.x += v.x; s.y += v.y; s.z += v.z; s.w += v.w;
  }
  ushort4 h;
  h.x = f2h(s.x); h.y = f2h(s.y); h.z = f2h(s.z); h.w = f2h(s.w);
  H[idx] = h;
}

// ---------- reduce -> bf16 (hi only; z's lo term is unused downstream) ----------
__global__ __launch_bounds__(256) void reduce_bf16(
    const float4* __restrict__ P, ushort4* __restrict__ H,
    int n4, int nsplit, int stride4) {
  int idx = blockIdx.x * 256 + threadIdx.x;
  if (idx >= n4) return;
  float4 s = P[idx];
  for (int sp = 1; sp < nsplit; ++sp) {
    float4 v = P[(size_t)sp * stride4 + idx];
    s.x += v.x; s.y += v.y; s.z += v.z; s.w += v.w;
  }
  ushort4 h;
  h.x = f2bf(s.x); h.y = f2bf(s.y); h.z = f2bf(s.z); h.w = f2bf(s.w);
  H[idx] = h;
}

// ---------- FUSED split GEMM (r9-proven body): C = Ah@Bl^T + Ah@Bh^T + Al@Bh^T ----------
// Sync skeleton tripwire-proven (r6-r14). K-split via blockIdx.y. fp32 C.
template<bool SWZ>
__global__ __launch_bounds__(512, 1) void gemm_fused3(
    const unsigned short* __restrict__ base,
    unsigned dAh, unsigned dAl, unsigned dBh, unsigned dBl,
    int N, int K, int kchunk, int tilesX,
    float* __restrict__ Cf, size_t partStride) {
  __shared__ unsigned short lds[65536];   // 2 slots x [Ah|Bh|Bl|Al] x 8192 ush
  const int AH = 0, BH = 8192, BL = 16384, AL = 24576;
  const int NT = kchunk >> 5;
  const int wg = blockIdx.x;
  int bx, by;
  if (SWZ) { const int sw = ((wg & 7) << 5) | (wg >> 3); bx = sw & 15; by = sw >> 4; }
  else     { bx = wg % tilesX; by = wg / tilesX; }
  const int m0 = by << 8, n0 = bx << 8;
  const unsigned koff = (unsigned)blockIdx.y * (unsigned)kchunk;
  Cf += (size_t)blockIdx.y * partStride;

  const int tid = threadIdx.x;
  const int w = tid >> 6, lane = tid & 63;
  const int wr = w >> 2, wc = w & 3;               // wave tile 128x64
  const int lr = lane & 15;
  const int phys = (lane >> 4) ^ ((lr >> 1) & 3);  // read-side swizzle
  const int aoff = (wr * 128 + lr) * 32 + phys * 8;   // + m*512
  const int boff = (wc * 64 + lr) * 32 + phys * 8;    // + n*512
  const int rst = tid >> 2;                            // staging source row
  const int ssrc = ((tid & 3) ^ ((tid >> 3) & 3)) * 8; // inverse-swizzled k-slot
  const unsigned jstep = 128u * (unsigned)K;

  const unsigned voffA = (unsigned)(m0 + rst) * (unsigned)K + (unsigned)ssrc + koff;
  const unsigned voffB = (unsigned)(n0 + rst) * (unsigned)K + (unsigned)ssrc + koff;

  f32x4 acc[8][4];
#pragma unroll
  for (int m = 0; m < 8; ++m)
#pragma unroll
    for (int n = 0; n < 4; ++n) acc[m][n] = {0.f, 0.f, 0.f, 0.f};

#define STG2(dsel, vo, loff, s, tt) do {                                     \
    const unsigned o_ = (vo) + (dsel) + (unsigned)(tt) * 32u;                \
    gload_lds16(base + o_,         &lds[(s) + (loff) + (w << 9)]);           \
    gload_lds16(base + o_ + jstep, &lds[(s) + (loff) + 4096 + (w << 9)]);    \
  } while (0)

  STG2(dAh, voffA, AH, 0, 0);
  STG2(dBl, voffB, BL, 0, 0);
  STG2(dBh, voffB, BH, 0, 0);
  STG2(dAl, voffA, AL, 0, 0);

  for (int t = 0; t < NT; ++t) {
    const int slot = (t & 1) << 15;
    const int slot1 = ((t + 1) & 1) << 15;
    const bool st = (t + 1) < NT;
    short8v ahf[8];                          // live across blocks 1-2
    SCHED; asm volatile("s_waitcnt vmcnt(4)"); SBAR; SCHED;
    {
      short8v bf[4];
#pragma unroll
      for (int n = 0; n < 4; ++n)
        bf[n] = *(const short8v*)&lds[slot + BL + boff + n * 512];
#pragma unroll
      for (int m = 0; m < 8; ++m)
        ahf[m] = *(const short8v*)&lds[slot + AH + aoff + m * 512];
      if (st) { STG2(dAh, voffA, AH, slot1, t + 1); STG2(dBl, voffB, BL, slot1, t + 1); }
      __builtin_amdgcn_s_setprio(1);
#pragma unroll
      for (int m = 0; m < 8; ++m)
#pragma unroll
        for (int n = 0; n < 4; ++n)
          acc[m][n] = __builtin_amdgcn_mfma_f32_16x16x32_bf16(ahf[m], bf[n], acc[m][n], 0, 0, 0);
      __builtin_amdgcn_s_setprio(0);
    }
    SCHED;
    if (st) { asm volatile("s_waitcnt vmcnt(6)"); }
    else    { asm volatile("s_waitcnt vmcnt(2)"); }
    SBAR; SCHED;
    short8v bh[4];                           // lives through block3
    {
#pragma unroll
      for (int n = 0; n < 4; ++n)
        bh[n] = *(const short8v*)&lds[slot + BH + boff + n * 512];
      if (st) { STG2(dBh, voffB, BH, slot1, t + 1); }
      __builtin_amdgcn_s_setprio(1);
#pragma unroll
      for (int m = 0; m < 8; ++m)
#pragma unroll
        for (int n = 0; n < 4; ++n)
          acc[m][n] = __builtin_amdgcn_mfma_f32_16x16x32_bf16(ahf[m], bh[n], acc[m][n], 0, 0, 0);
      __builtin_amdgcn_s_setprio(0);
    }
    SCHED;
    if (st) { asm volatile("s_waitcnt vmcnt(6)"); }
    else    { asm volatile("s_waitcnt vmcnt(0)"); }
    SBAR; SCHED;
    {
      short8v alf[8];
#pragma unroll
      for (int m = 0; m < 8; ++m)
        alf[m] = *(const short8v*)&lds[slot + AL + aoff + m * 512];
      if (st) { STG2(dAl, voffA, AL, slot1, t + 1); }
      __builtin_amdgcn_s_setprio(1);
#pragma unroll
      for (int m = 0; m < 8; ++m)
#pragma unroll
        for (int n = 0; n < 4; ++n)
          acc[m][n] = __builtin_amdgcn_mfma_f32_16x16x32_bf16(alf[m], bh[n], acc[m][n], 0, 0, 0);
      __builtin_amdgcn_s_setprio(0);
    }
    SCHED;
  }
#undef STG2

  const int crow = m0 + wr * 128 + ((lane >> 4) << 2);
  const int ccol = n0 + wc * 64 + lr;
#pragma unroll
  for (int mi = 0; mi < 8; ++mi)
#pragma unroll
    for (int r = 0; r < 4; ++r) {
      const int row = crow + mi * 16 + r;
#pragma unroll
      for (int n = 0; n < 4; ++n)
        Cf[(size_t)row * N + ccol + n * 16] = acc[mi][n][r];
    }
}

// ---------- 128x128-tile single-pass GEMM: C = A @ B^T ----------
// r9 skeleton reparameterized: 256 thr / 4 waves (2x2, wave-tile 64x64),
// BK=32, 4-slot ring = 64 KiB -> 2 blocks/CU (independent barrier groups
// overlap; m97 mechanism). vmcnt ledger identical: 4 stage-ops/tile, 8/4/0.
// Swizzle identity ((r>>1)&3 == (lane>>3)&3) re-verified for 64-row strides.
// DT 0: bf16 MFMA; 1: f16 MFMA. fp32 C (+K-split partials).
template<bool SWZ, int DT>
__global__ __launch_bounds__(256, 2) void gemm_plain128(
    const unsigned short* __restrict__ A, const unsigned short* __restrict__ B,
    int N, int K, int kchunk, int tilesX,
    float* __restrict__ Cf, size_t partStride) {
  __shared__ unsigned short lds[32768];   // 4 slots x (A 4096 + B 4096) ush
  const int NT = kchunk >> 5;
  const int wg = blockIdx.x;
  int bx, by;
  if (SWZ) { const int sw = ((wg & 7) << 7) | (wg >> 3); bx = sw & 31; by = sw >> 5; }
  else     { bx = wg % tilesX; by = wg / tilesX; }
  const int m0 = by << 7, n0 = bx << 7;
  const unsigned koff = (unsigned)blockIdx.y * (unsigned)kchunk;
  Cf += (size_t)blockIdx.y * partStride;

  const int tid = threadIdx.x;
  const int w = tid >> 6, lane = tid & 63;
  const int wr = w >> 1, wc = w & 1;          // 2x2 waves
  const int lr = lane & 15;
  const int phys = (lane >> 4) ^ ((lr >> 1) & 3);
  const int aoff = (wr * 64 + lr) * 32 + phys * 8;          // + m*512
  const int boff = 4096 + (wc * 64 + lr) * 32 + phys * 8;   // + n*512
  const int rst = w * 16 + (lane >> 2);       // staging source row (op j=0)
  const int ssrc = ((lane & 3) ^ ((lane >> 3) & 3)) * 8;

  f32x4 acc[4][4];
#pragma unroll
  for (int m = 0; m < 4; ++m)
#pragma unroll
    for (int n = 0; n < 4; ++n) acc[m][n] = {0.f, 0.f, 0.f, 0.f};

  const unsigned short* gA = A + (size_t)(m0 + rst) * K + ssrc + koff;
  const unsigned short* gB = B + (size_t)(n0 + rst) * K + ssrc + koff;
  const size_t jstep = (size_t)64 * K;

#define MFMA_DT(af, bf, c) (DT == 1 ? \
    __builtin_amdgcn_mfma_f32_16x16x32_f16(__builtin_bit_cast(half8v, af), \
        __builtin_bit_cast(half8v, bf), (c), 0, 0, 0) : \
    __builtin_amdgcn_mfma_f32_16x16x32_bf16((af), (bf), (c), 0, 0, 0))

  // prologue: stage tiles 0..2 into slots 0..2 (4 ops each)
#pragma unroll
  for (int tau = 0; tau < 3; ++tau) {
    const int so = tau * 8192 + (w << 9);
    gload_lds16(gA + (size_t)tau * 32, &lds[so]);
    gload_lds16(gA + (size_t)tau * 32 + jstep, &lds[so + 2048]);
    gload_lds16(gB + (size_t)tau * 32, &lds[so + 4096]);
    gload_lds16(gB + (size_t)tau * 32 + jstep, &lds[so + 6144]);
  }
  asm volatile("s_waitcnt vmcnt(8)");
  SCHED; SBAR; SCHED;

  for (int t = 0; t < NT; ++t) {
    const int sb = (t & 3) * 8192;
    if (t + 3 < NT) {
      const int so = ((t + 3) & 3) * 8192 + (w << 9);
      const unsigned short* srcA = gA + (size_t)(t + 3) * 32;
      const unsigned short* srcB = gB + (size_t)(t + 3) * 32;
      gload_lds16(srcA, &lds[so]);
      gload_lds16(srcA + jstep, &lds[so + 2048]);
      gload_lds16(srcB, &lds[so + 4096]);
      gload_lds16(srcB + jstep, &lds[so + 6144]);
    }
    short8v bfr[4], af[4];
#pragma unroll
    for (int n = 0; n < 4; ++n)
      bfr[n] = *(const short8v*)&lds[sb + boff + n * 512];
#pragma unroll
    for (int m = 0; m < 4; ++m)
      af[m] = *(const short8v*)&lds[sb + aoff + m * 512];
    __builtin_amdgcn_s_setprio(1);
#pragma unroll
    for (int m = 0; m < 4; ++m)
#pragma unroll
      for (int n = 0; n < 4; ++n)
        acc[m][n] = MFMA_DT(af[m], bfr[n], acc[m][n]);
    __builtin_amdgcn_s_setprio(0);
    SCHED;
    if (t < NT - 3)       { asm volatile("s_waitcnt vmcnt(8)"); }
    else if (t == NT - 3) { asm volatile("s_waitcnt vmcnt(4)"); }
    else if (t == NT - 2) { asm volatile("s_waitcnt vmcnt(0)"); }
    SCHED;
    if (t < NT - 1) { SBAR; SCHED; }
  }
#undef MFMA_DT

  const int crow = m0 + wr * 64 + ((lane >> 4) << 2);
  const int ccol = n0 + wc * 64 + lr;
#pragma unroll
  for (int mi = 0; mi < 4; ++mi)
#pragma unroll
    for (int r = 0; r < 4; ++r) {
      const int row = crow + mi * 16 + r;
#pragma unroll
      for (int n = 0; n < 4; ++n)
        Cf[(size_t)row * N + ccol + n * 16] = acc[mi][n][r];
    }
}

// ---------- row softmax: fp32 (n per row) -> bf16 p ----------
__global__ __launch_bounds__(256) void softmax_rows(
    const float* __restrict__ S, unsigned short* __restrict__ P, int n) {
  const int row = blockIdx.x;
  const int t = threadIdx.x;
  const float4* src = (const float4*)(S + (size_t)row * n);
  float4 v[4];
  float mx = -3.0e38f;
#pragma unroll
  for (int i = 0; i < 4; ++i) {
    v[i] = src[i * 256 + t];
    mx = fmaxf(mx, fmaxf(fmaxf(v[i].x, v[i].y), fmaxf(v[i].z, v[i].w)));
  }
#pragma unroll
  for (int off = 32; off; off >>= 1) mx = fmaxf(mx, __shfl_xor(mx, off));
  __shared__ float redm[4], reds[4];
  const int wid = t >> 6, lane = t & 63;
  if (lane == 0) redm[wid] = mx;
  __syncthreads();
  mx = fmaxf(fmaxf(redm[0], redm[1]), fmaxf(redm[2], redm[3]));
  float sum = 0.f;
#pragma unroll
  for (int i = 0; i < 4; ++i) {
    v[i].x = __expf(v[i].x - mx);
    v[i].y = __expf(v[i].y - mx);
    v[i].z = __expf(v[i].z - mx);
    v[i].w = __expf(v[i].w - mx);
    sum += (v[i].x + v[i].y) + (v[i].z + v[i].w);
  }
#pragma unroll
  for (int off = 32; off; off >>= 1) sum += __shfl_xor(sum, off);
  if (lane == 0) reds[wid] = sum;
  __syncthreads();
  sum = (reds[0] + reds[1]) + (reds[2] + reds[3]);
  float inv = 1.0f / sum;
#pragma unroll
  for (int i = 0; i < 4; ++i) {
    ushort4 o;
    o.x = f2bf(v[i].x * inv);
    o.y = f2bf(v[i].y * inv);
    o.z = f2bf(v[i].z * inv);
    o.w = f2bf(v[i].w * inv);
    *(ushort4*)(P + (size_t)row * n + (size_t)(i * 256 + t) * 4) = o;
  }
}

// ---------- launch ----------
extern "C" void kernel_launch(void* const* d_in, const int* in_sizes, int n_in,
                              void* d_out, int out_size, void* d_ws, size_t ws_size,
                              hipStream_t stream) {
  (void)in_sizes; (void)n_in; (void)out_size; (void)ws_size;
  const float* x  = (const float*)d_in[0];
  const float* Wq = (const float*)d_in[1];
  const float* Wk = (const float*)d_in[2];
  const float* Wv = (const float*)d_in[3];
  const int N = 4096, D = 1024;
  const size_t MB = 1ull << 20;
  const unsigned MEL = (unsigned)(MB / 2);   // 16-bit elements per MB
  char* ws = (char*)d_ws;
  unsigned short* xh  = (unsigned short*)(ws + 0 * MB);
  unsigned short* xl  = (unsigned short*)(ws + 8 * MB);
  unsigned short* wqh = (unsigned short*)(ws + 16 * MB);   // dead after M
  unsigned short* wql = (unsigned short*)(ws + 24 * MB);
  unsigned short* wkh = (unsigned short*)(ws + 32 * MB);   // dead after M
  unsigned short* wkl = (unsigned short*)(ws + 40 * MB);
  unsigned short* wvh = (unsigned short*)(ws + 48 * MB);   // live till out GEMM
  unsigned short* Mth = (unsigned short*)(ws + 56 * MB);   // 2 MB
  unsigned short* Mtl = (unsigned short*)(ws + 58 * MB);   // 2 MB
  unsigned short* p   = (unsigned short*)(ws + 64 * MB);   // 32 MB
  float*          Mpart = (float*)(ws + 96 * MB);          // 16 x 4 MB
  float*          ypart = (float*)(ws + 96 * MB);
  float*          zpart = (float*)(ws + 96 * MB);
  unsigned short* y16 = (unsigned short*)(ws + 16 * MB);   // over wqh (after M)
  unsigned short* zh  = (unsigned short*)(ws + 32 * MB);   // over wkh (after M)
  unsigned short* xTh = (unsigned short*)(ws + 160 * MB);  // 8 MB
  unsigned short* x16 = (unsigned short*)(ws + 184 * MB);  // 8 MB
  float* score = (float*)d_out;
  float* out   = (float*)d_out;

  // 1) splits / converts
  split_x3<<<4096, 256, 0, stream>>>((const float4*)x, (ushort4*)xh, (ushort4*)xl,
                                     (ushort4*)x16, 1048576);
  split_plain<<<4096, 256, 0, stream>>>((const float4*)Wq, (ushort4*)wqh, (ushort4*)wql, 1048576);
  split_plain<<<4096, 256, 0, stream>>>((const float4*)Wk, (ushort4*)wkh, (ushort4*)wkl, 1048576);
  split_T<false><<<dim3(N / 32, D / 32), 256, 0, stream>>>(Wv, wvh, nullptr, D, N);  // wvh = Wv^T
  split_T<false><<<dim3(D / 32, N / 32), 256, 0, stream>>>(x, xTh, nullptr, N, D);   // xTh = x^T

  // 2) M = Wq @ Wk^T (1024x1024, K=4096), 3-pass split, 16-way K-split (256 wg)
  gemm_fused3<false><<<dim3(16, 16), 512, 0, stream>>>(
      wqh, 0u, 8 * MEL, 16 * MEL, 24 * MEL,
      1024, 4096, 256, 4, Mpart, (size_t)1024 * 1024);
  // 3) Mt = transpose(sum Mpart) -> split hi/lo bf16
  reduceT_M<<<dim3(32, 32), 256, 0, stream>>>(Mpart, Mth, Mtl, 16);

  // 4) y = x @ Mt^T (4096x1024, K=1024), 3-pass split, 4-way K-split (256 wg)
  gemm_fused3<false><<<dim3(64, 4), 512, 0, stream>>>(
      xh, 0u, 8 * MEL, 56 * MEL, 58 * MEL,
      1024, 1024, 256, 4, ypart, (size_t)4096 * 1024);
  // 5) y16 = f16(sum ypart)
  reduce_f16<<<4096, 256, 0, stream>>>(
      (const float4*)ypart, (ushort4*)y16, 1048576, 4, 1048576);

  // 6) score = y16 @ x16^T (4096x4096, K=1024), single f16 pass -> fp32 d_out
  gemm_plain128<true, 1><<<dim3(1024, 1), 256, 0, stream>>>(
      y16, x16, N, 1024, 1024, 32, score, 0);

  // 7) p = softmax(score) -> bf16
  softmax_rows<<<N, 256, 0, stream>>>(score, p, N);

  // 8) z = p @ x (4096x1024, K=4096) via B=xT; 4-way K-split -> fp32 partials
  gemm_plain128<false, 0><<<dim3(256, 4), 256, 0, stream>>>(
      p, xTh, 1024, 4096, 1024, 8, zpart, (size_t)4096 * 1024);
  // 9) zh = bf16(sum zpart)  (lo term unused downstream)
  reduce_bf16<<<4096, 256, 0, stream>>>(
      (const float4*)zpart, (ushort4*)zh, 1048576, 4, 1048576);

  // 10) out = z @ Wv = zh @ wvh^T (4096x4096, K=1024) -> fp32 d_out
  gemm_plain128<true, 0><<<dim3(1024, 1), 256, 0, stream>>>(
      zh, wvh, N, 1024, 1024, 32, out, 0);
}

// Round 17
// 292.005 us; speedup vs baseline: 1.0846x; 1.0846x over previous
//
#include <hip/hip_runtime.h>
#include <hip/hip_bf16.h>
#include <stdint.h>

// ---------- helpers ----------
typedef __attribute__((ext_vector_type(8))) short short8v;    // 8 x 16-bit (4 VGPRs)
typedef __attribute__((ext_vector_type(8))) _Float16 half8v;  // 8 x f16
typedef __attribute__((ext_vector_type(4))) float f32x4;

__device__ __forceinline__ unsigned short f2bf(float f) {
  unsigned u = __builtin_bit_cast(unsigned, f);
  unsigned r = 0x7fffu + ((u >> 16) & 1u);          // round-to-nearest-even
  return (unsigned short)((u + r) >> 16);
}
__device__ __forceinline__ float bf2f(unsigned short h) {
  unsigned u = ((unsigned)h) << 16;
  return __builtin_bit_cast(float, u);
}
__device__ __forceinline__ unsigned short f2h(float f) {
  _Float16 h = (_Float16)f;                         // RTNE
  return __builtin_bit_cast(unsigned short, h);
}
__device__ __forceinline__ void gload_lds16(const void* g, void* l) {
  __builtin_amdgcn_global_load_lds(
      (const __attribute__((address_space(1))) void*)g,
      (__attribute__((address_space(3))) void*)l, 16, 0, 0);
}
#define SBAR  __builtin_amdgcn_s_barrier()
#define SCHED __builtin_amdgcn_sched_barrier(0)

// ---------- split / convert kernels ----------
__global__ __launch_bounds__(256) void split_plain(
    const float4* __restrict__ X, ushort4* __restrict__ H, ushort4* __restrict__ L, int n4) {
  int idx = blockIdx.x * 256 + threadIdx.x;
  if (idx >= n4) return;
  float4 v = X[idx];
  ushort4 h, l;
  h.x = f2bf(v.x); l.x = f2bf(v.x - bf2f(h.x));
  h.y = f2bf(v.y); l.y = f2bf(v.y - bf2f(h.y));
  h.z = f2bf(v.z); l.z = f2bf(v.z - bf2f(h.z));
  h.w = f2bf(v.w); l.w = f2bf(v.w - bf2f(h.w));
  H[idx] = h; L[idx] = l;
}

// x: one pass -> bf16 hi/lo + f16 copy
__global__ __launch_bounds__(256) void split_x3(
    const float4* __restrict__ X, ushort4* __restrict__ H, ushort4* __restrict__ L,
    ushort4* __restrict__ F, int n4) {
  int idx = blockIdx.x * 256 + threadIdx.x;
  if (idx >= n4) return;
  float4 v = X[idx];
  ushort4 h, l, f;
  h.x = f2bf(v.x); l.x = f2bf(v.x - bf2f(h.x)); f.x = f2h(v.x);
  h.y = f2bf(v.y); l.y = f2bf(v.y - bf2f(h.y)); f.y = f2h(v.y);
  h.z = f2bf(v.z); l.z = f2bf(v.z - bf2f(h.z)); f.z = f2h(v.z);
  h.w = f2bf(v.w); l.w = f2bf(v.w - bf2f(h.w)); f.w = f2h(v.w);
  H[idx] = h; L[idx] = l; F[idx] = f;
}

template<bool WL>
__global__ __launch_bounds__(256) void split_T(
    const float* __restrict__ W, unsigned short* __restrict__ H,
    unsigned short* __restrict__ L, int Kd, int Nd) {
  __shared__ float tile[32][33];
  const int t = threadIdx.x;
  const int c = t & 31;
  const int r0 = t >> 5;
  const int k0 = blockIdx.y * 32, n0 = blockIdx.x * 32;
#pragma unroll
  for (int i = 0; i < 4; ++i) {
    int r = r0 + i * 8;
    tile[r][c] = W[(size_t)(k0 + r) * Nd + n0 + c];
  }
  __syncthreads();
#pragma unroll
  for (int i = 0; i < 4; ++i) {
    int n = r0 + i * 8;
    float f = tile[c][n];
    unsigned short h = f2bf(f);
    size_t o = (size_t)(n0 + n) * Kd + k0 + c;
    H[o] = h;
    if (WL) L[o] = f2bf(f - bf2f(h));
  }
}

// ---------- M-transpose reduce: Mt[b][a] = split(sum_s Mpart[s][a][b]) ----------
__global__ __launch_bounds__(256) void reduceT_M(
    const float* __restrict__ P, unsigned short* __restrict__ H,
    unsigned short* __restrict__ L, int nsplit) {
  __shared__ float tile[32][33];
  const int t = threadIdx.x;
  const int c = t & 31;
  const int r0 = t >> 5;
  const int a0 = blockIdx.y * 32, b0 = blockIdx.x * 32;
#pragma unroll
  for (int i = 0; i < 4; ++i) {
    int r = r0 + i * 8;
    float s = 0.f;
    for (int sp = 0; sp < nsplit; ++sp)
      s += P[(size_t)sp * 1048576 + (size_t)(a0 + r) * 1024 + b0 + c];
    tile[r][c] = s;
  }
  __syncthreads();
#pragma unroll
  for (int i = 0; i < 4; ++i) {
    int b = r0 + i * 8;
    float f = tile[c][b];                 // = M[a0+c][b0+b]
    unsigned short h = f2bf(f);
    size_t o = (size_t)(b0 + b) * 1024 + a0 + c;   // Mt[b][a]
    H[o] = h;
    L[o] = f2bf(f - bf2f(h));
  }
}

// ---------- reduce -> f16 ----------
__global__ __launch_bounds__(256) void reduce_f16(
    const float4* __restrict__ P, ushort4* __restrict__ H,
    int n4, int nsplit, int stride4) {
  int idx = blockIdx.x * 256 + threadIdx.x;
  if (idx >= n4) return;
  float4 s = P[idx];
  for (int sp = 1; sp < nsplit; ++sp) {
    float4 v = P[(size_t)sp * stride4 + idx];
    s.x += v.x; s.y += v.y; s.z += v.z; s.w += v.w;
  }
  ushort4 h;
  h.x = f2h(s.x); h.y = f2h(s.y); h.z = f2h(s.z); h.w = f2h(s.w);
  H[idx] = h;
}

// ---------- reduce -> bf16 (hi only; z's lo term is unused downstream) ----------
__global__ __launch_bounds__(256) void reduce_bf16(
    const float4* __restrict__ P, ushort4* __restrict__ H,
    int n4, int nsplit, int stride4) {
  int idx = blockIdx.x * 256 + threadIdx.x;
  if (idx >= n4) return;
  float4 s = P[idx];
  for (int sp = 1; sp < nsplit; ++sp) {
    float4 v = P[(size_t)sp * stride4 + idx];
    s.x += v.x; s.y += v.y; s.z += v.z; s.w += v.w;
  }
  ushort4 h;
  h.x = f2bf(s.x); h.y = f2bf(s.y); h.z = f2bf(s.z); h.w = f2bf(s.w);
  H[idx] = h;
}

// ---------- FUSED split GEMM (r9-proven body): C = Ah@Bl^T + Ah@Bh^T + Al@Bh^T ----------
// Sync skeleton tripwire-proven (r6-r15). K-split via blockIdx.y. fp32 C.
template<bool SWZ>
__global__ __launch_bounds__(512, 1) void gemm_fused3(
    const unsigned short* __restrict__ base,
    unsigned dAh, unsigned dAl, unsigned dBh, unsigned dBl,
    int N, int K, int kchunk, int tilesX,
    float* __restrict__ Cf, size_t partStride) {
  __shared__ unsigned short lds[65536];   // 2 slots x [Ah|Bh|Bl|Al] x 8192 ush
  const int AH = 0, BH = 8192, BL = 16384, AL = 24576;
  const int NT = kchunk >> 5;
  const int wg = blockIdx.x;
  int bx, by;
  if (SWZ) { const int sw = ((wg & 7) << 5) | (wg >> 3); bx = sw & 15; by = sw >> 4; }
  else     { bx = wg % tilesX; by = wg / tilesX; }
  const int m0 = by << 8, n0 = bx << 8;
  const unsigned koff = (unsigned)blockIdx.y * (unsigned)kchunk;
  Cf += (size_t)blockIdx.y * partStride;

  const int tid = threadIdx.x;
  const int w = tid >> 6, lane = tid & 63;
  const int wr = w >> 2, wc = w & 3;               // wave tile 128x64
  const int lr = lane & 15;
  const int phys = (lane >> 4) ^ ((lr >> 1) & 3);  // read-side swizzle
  const int aoff = (wr * 128 + lr) * 32 + phys * 8;   // + m*512
  const int boff = (wc * 64 + lr) * 32 + phys * 8;    // + n*512
  const int rst = tid >> 2;                            // staging source row
  const int ssrc = ((tid & 3) ^ ((tid >> 3) & 3)) * 8; // inverse-swizzled k-slot
  const unsigned jstep = 128u * (unsigned)K;

  const unsigned voffA = (unsigned)(m0 + rst) * (unsigned)K + (unsigned)ssrc + koff;
  const unsigned voffB = (unsigned)(n0 + rst) * (unsigned)K + (unsigned)ssrc + koff;

  f32x4 acc[8][4];
#pragma unroll
  for (int m = 0; m < 8; ++m)
#pragma unroll
    for (int n = 0; n < 4; ++n) acc[m][n] = {0.f, 0.f, 0.f, 0.f};

#define STG2(dsel, vo, loff, s, tt) do {                                     \
    const unsigned o_ = (vo) + (dsel) + (unsigned)(tt) * 32u;                \
    gload_lds16(base + o_,         &lds[(s) + (loff) + (w << 9)]);           \
    gload_lds16(base + o_ + jstep, &lds[(s) + (loff) + 4096 + (w << 9)]);    \
  } while (0)

  STG2(dAh, voffA, AH, 0, 0);
  STG2(dBl, voffB, BL, 0, 0);
  STG2(dBh, voffB, BH, 0, 0);
  STG2(dAl, voffA, AL, 0, 0);

  for (int t = 0; t < NT; ++t) {
    const int slot = (t & 1) << 15;
    const int slot1 = ((t + 1) & 1) << 15;
    const bool st = (t + 1) < NT;
    short8v ahf[8];                          // live across blocks 1-2
    SCHED; asm volatile("s_waitcnt vmcnt(4)"); SBAR; SCHED;
    {
      short8v bf[4];
#pragma unroll
      for (int n = 0; n < 4; ++n)
        bf[n] = *(const short8v*)&lds[slot + BL + boff + n * 512];
#pragma unroll
      for (int m = 0; m < 8; ++m)
        ahf[m] = *(const short8v*)&lds[slot + AH + aoff + m * 512];
      if (st) { STG2(dAh, voffA, AH, slot1, t + 1); STG2(dBl, voffB, BL, slot1, t + 1); }
      __builtin_amdgcn_s_setprio(1);
#pragma unroll
      for (int m = 0; m < 8; ++m)
#pragma unroll
        for (int n = 0; n < 4; ++n)
          acc[m][n] = __builtin_amdgcn_mfma_f32_16x16x32_bf16(ahf[m], bf[n], acc[m][n], 0, 0, 0);
      __builtin_amdgcn_s_setprio(0);
    }
    SCHED;
    if (st) { asm volatile("s_waitcnt vmcnt(6)"); }
    else    { asm volatile("s_waitcnt vmcnt(2)"); }
    SBAR; SCHED;
    short8v bh[4];                           // lives through block3
    {
#pragma unroll
      for (int n = 0; n < 4; ++n)
        bh[n] = *(const short8v*)&lds[slot + BH + boff + n * 512];
      if (st) { STG2(dBh, voffB, BH, slot1, t + 1); }
      __builtin_amdgcn_s_setprio(1);
#pragma unroll
      for (int m = 0; m < 8; ++m)
#pragma unroll
        for (int n = 0; n < 4; ++n)
          acc[m][n] = __builtin_amdgcn_mfma_f32_16x16x32_bf16(ahf[m], bh[n], acc[m][n], 0, 0, 0);
      __builtin_amdgcn_s_setprio(0);
    }
    SCHED;
    if (st) { asm volatile("s_waitcnt vmcnt(6)"); }
    else    { asm volatile("s_waitcnt vmcnt(0)"); }
    SBAR; SCHED;
    {
      short8v alf[8];
#pragma unroll
      for (int m = 0; m < 8; ++m)
        alf[m] = *(const short8v*)&lds[slot + AL + aoff + m * 512];
      if (st) { STG2(dAl, voffA, AL, slot1, t + 1); }
      __builtin_amdgcn_s_setprio(1);
#pragma unroll
      for (int m = 0; m < 8; ++m)
#pragma unroll
        for (int n = 0; n < 4; ++n)
          acc[m][n] = __builtin_amdgcn_mfma_f32_16x16x32_bf16(alf[m], bh[n], acc[m][n], 0, 0, 0);
      __builtin_amdgcn_s_setprio(0);
    }
    SCHED;
  }
#undef STG2

  const int crow = m0 + wr * 128 + ((lane >> 4) << 2);
  const int ccol = n0 + wc * 64 + lr;
#pragma unroll
  for (int mi = 0; mi < 8; ++mi)
#pragma unroll
    for (int r = 0; r < 4; ++r) {
      const int row = crow + mi * 16 + r;
#pragma unroll
      for (int n = 0; n < 4; ++n)
        Cf[(size_t)row * N + ccol + n * 16] = acc[mi][n][r];
    }
}

// ---------- plain single-pass GEMM (r15-proven body): C = A @ B^T ----------
// 512 thr / 8 waves, 256x256 tile, 4-slot ring, counted vmcnt 8/4/0 before
// the barrier, one SBAR per tile. r17 change: SWZ uses an XCD SUPER-TILE map
// (each XCD owns 8 blocks of 2x2 tiles -> per-XCD working set 2A+2B panels
// = 2 MB < 4 MB L2; pure index permutation, K-order untouched -> bit-identical).
// DT 0: bf16 MFMA; 1: f16 MFMA (same fragment/C-D layout, m121/m123). fp32 C.
template<bool SWZ, int DT>
__global__ __launch_bounds__(512, 2) void gemm_plain(
    const unsigned short* __restrict__ A, const unsigned short* __restrict__ B,
    int N, int K, int kchunk, int tilesX,
    float* __restrict__ Cf, size_t partStride) {
  __shared__ unsigned short lds[65536];   // 4 slots x (A 8192 + B 8192)
  const int NT = kchunk >> 5;
  const int wg = blockIdx.x;
  int bx, by;
  if (SWZ) {
    // super-tile map for a 16x16 tile grid (256 wg): xcd -> 8 supers of 2x2
    const int xcd = wg & 7, idx = wg >> 3;         // idx 0..31
    const int sg = (idx >> 2) * 8 + xcd;           // super 0..63 on 8x8 grid
    by = ((sg >> 3) << 1) + ((idx >> 1) & 1);
    bx = ((sg & 7) << 1) + (idx & 1);
  } else { bx = wg % tilesX; by = wg / tilesX; }
  const int m0 = by << 8, n0 = bx << 8;
  const unsigned koff = (unsigned)blockIdx.y * (unsigned)kchunk;
  Cf += (size_t)blockIdx.y * partStride;

  const int tid = threadIdx.x;
  const int w = tid >> 6, lane = tid & 63;
  const int wr = w >> 2, wc = w & 3;
  const int lr = lane & 15;
  const int phys = (lane >> 4) ^ ((lr >> 1) & 3);
  const int aoff = (wr * 128 + lr) * 32 + phys * 8;
  const int boff = 8192 + (wc * 64 + lr) * 32 + phys * 8;
  const int rst = w * 16 + (lane >> 2);
  const int ssrc = ((lane & 3) ^ ((lane >> 3) & 3)) * 8;

  f32x4 acc[8][4];
#pragma unroll
  for (int m = 0; m < 8; ++m)
#pragma unroll
    for (int n = 0; n < 4; ++n) acc[m][n] = {0.f, 0.f, 0.f, 0.f};

  const unsigned short* gA = A + (size_t)(m0 + rst) * K + ssrc + koff;
  const unsigned short* gB = B + (size_t)(n0 + rst) * K + ssrc + koff;
  const size_t jstep = (size_t)128 * K;

#define MFMA_DT(af, bf, c) (DT == 1 ? \
    __builtin_amdgcn_mfma_f32_16x16x32_f16(__builtin_bit_cast(half8v, af), \
        __builtin_bit_cast(half8v, bf), (c), 0, 0, 0) : \
    __builtin_amdgcn_mfma_f32_16x16x32_bf16((af), (bf), (c), 0, 0, 0))

  // prologue: stage tiles 0..2 into slots 0..2
#pragma unroll
  for (int tau = 0; tau < 3; ++tau) {
    const int so = tau * 16384 + (w << 9);
    gload_lds16(gA + (size_t)tau * 32, &lds[so]);
    gload_lds16(gA + (size_t)tau * 32 + jstep, &lds[so + 4096]);
    gload_lds16(gB + (size_t)tau * 32, &lds[so + 8192]);
    gload_lds16(gB + (size_t)tau * 32 + jstep, &lds[so + 12288]);
  }
  asm volatile("s_waitcnt vmcnt(8)");
  SCHED; SBAR; SCHED;

  for (int t = 0; t < NT; ++t) {
    const int sb = (t & 3) * 16384;
    if (t + 3 < NT) {
      const int so = ((t + 3) & 3) * 16384 + (w << 9);
      const unsigned short* srcA = gA + (size_t)(t + 3) * 32;
      const unsigned short* srcB = gB + (size_t)(t + 3) * 32;
      gload_lds16(srcA, &lds[so]);
      gload_lds16(srcA + jstep, &lds[so + 4096]);
      gload_lds16(srcB, &lds[so + 8192]);
      gload_lds16(srcB + jstep, &lds[so + 12288]);
    }
    short8v bfr[4], af0[4], af1[4];
#pragma unroll
    for (int n = 0; n < 4; ++n)
      bfr[n] = *(const short8v*)&lds[sb + boff + n * 512];
#pragma unroll
    for (int m = 0; m < 4; ++m)
      af0[m] = *(const short8v*)&lds[sb + aoff + m * 512];
#pragma unroll
    for (int m = 0; m < 4; ++m)
      af1[m] = *(const short8v*)&lds[sb + aoff + 2048 + m * 512];
    __builtin_amdgcn_s_setprio(1);
#pragma unroll
    for (int m = 0; m < 4; ++m)
#pragma unroll
      for (int n = 0; n < 4; ++n)
        acc[m][n] = MFMA_DT(af0[m], bfr[n], acc[m][n]);
#pragma unroll
    for (int m = 0; m < 4; ++m)
#pragma unroll
      for (int n = 0; n < 4; ++n)
        acc[4 + m][n] = MFMA_DT(af1[m], bfr[n], acc[4 + m][n]);
    __builtin_amdgcn_s_setprio(0);
    SCHED;
    if (t < NT - 3)       { asm volatile("s_waitcnt vmcnt(8)"); }
    else if (t == NT - 3) { asm volatile("s_waitcnt vmcnt(4)"); }
    else if (t == NT - 2) { asm volatile("s_waitcnt vmcnt(0)"); }
    SCHED;
    if (t < NT - 1) { SBAR; SCHED; }
  }
#undef MFMA_DT

  const int crow = m0 + wr * 128 + ((lane >> 4) << 2);
  const int ccol = n0 + wc * 64 + lr;
#pragma unroll
  for (int mi = 0; mi < 8; ++mi)
#pragma unroll
    for (int r = 0; r < 4; ++r) {
      const int row = crow + mi * 16 + r;
#pragma unroll
      for (int n = 0; n < 4; ++n)
        Cf[(size_t)row * N + ccol + n * 16] = acc[mi][n][r];
    }
}

// ---------- row softmax: fp32 (n per row) -> bf16 p ----------
__global__ __launch_bounds__(256) void softmax_rows(
    const float* __restrict__ S, unsigned short* __restrict__ P, int n) {
  const int row = blockIdx.x;
  const int t = threadIdx.x;
  const float4* src = (const float4*)(S + (size_t)row * n);
  float4 v[4];
  float mx = -3.0e38f;
#pragma unroll
  for (int i = 0; i < 4; ++i) {
    v[i] = src[i * 256 + t];
    mx = fmaxf(mx, fmaxf(fmaxf(v[i].x, v[i].y), fmaxf(v[i].z, v[i].w)));
  }
#pragma unroll
  for (int off = 32; off; off >>= 1) mx = fmaxf(mx, __shfl_xor(mx, off));
  __shared__ float redm[4], reds[4];
  const int wid = t >> 6, lane = t & 63;
  if (lane == 0) redm[wid] = mx;
  __syncthreads();
  mx = fmaxf(fmaxf(redm[0], redm[1]), fmaxf(redm[2], redm[3]));
  float sum = 0.f;
#pragma unroll
  for (int i = 0; i < 4; ++i) {
    v[i].x = __expf(v[i].x - mx);
    v[i].y = __expf(v[i].y - mx);
    v[i].z = __expf(v[i].z - mx);
    v[i].w = __expf(v[i].w - mx);
    sum += (v[i].x + v[i].y) + (v[i].z + v[i].w);
  }
#pragma unroll
  for (int off = 32; off; off >>= 1) sum += __shfl_xor(sum, off);
  if (lane == 0) reds[wid] = sum;
  __syncthreads();
  sum = (reds[0] + reds[1]) + (reds[2] + reds[3]);
  float inv = 1.0f / sum;
#pragma unroll
  for (int i = 0; i < 4; ++i) {
    ushort4 o;
    o.x = f2bf(v[i].x * inv);
    o.y = f2bf(v[i].y * inv);
    o.z = f2bf(v[i].z * inv);
    o.w = f2bf(v[i].w * inv);
    *(ushort4*)(P + (size_t)row * n + (size_t)(i * 256 + t) * 4) = o;
  }
}

// ---------- launch ----------
extern "C" void kernel_launch(void* const* d_in, const int* in_sizes, int n_in,
                              void* d_out, int out_size, void* d_ws, size_t ws_size,
                              hipStream_t stream) {
  (void)in_sizes; (void)n_in; (void)out_size; (void)ws_size;
  const float* x  = (const float*)d_in[0];
  const float* Wq = (const float*)d_in[1];
  const float* Wk = (const float*)d_in[2];
  const float* Wv = (const float*)d_in[3];
  const int N = 4096, D = 1024;
  const size_t MB = 1ull << 20;
  const unsigned MEL = (unsigned)(MB / 2);   // 16-bit elements per MB
  char* ws = (char*)d_ws;
  unsigned short* xh  = (unsigned short*)(ws + 0 * MB);
  unsigned short* xl  = (unsigned short*)(ws + 8 * MB);
  unsigned short* wqh = (unsigned short*)(ws + 16 * MB);   // dead after M
  unsigned short* wql = (unsigned short*)(ws + 24 * MB);
  unsigned short* wkh = (unsigned short*)(ws + 32 * MB);   // dead after M
  unsigned short* wkl = (unsigned short*)(ws + 40 * MB);
  unsigned short* wvh = (unsigned short*)(ws + 48 * MB);   // live till out GEMM
  unsigned short* Mth = (unsigned short*)(ws + 56 * MB);   // 2 MB
  unsigned short* Mtl = (unsigned short*)(ws + 58 * MB);   // 2 MB
  unsigned short* p   = (unsigned short*)(ws + 64 * MB);   // 32 MB
  float*          Mpart = (float*)(ws + 96 * MB);          // 16 x 4 MB
  float*          ypart = (float*)(ws + 96 * MB);
  float*          zpart = (float*)(ws + 96 * MB);
  unsigned short* y16 = (unsigned short*)(ws + 16 * MB);   // over wqh (after M)
  unsigned short* zh  = (unsigned short*)(ws + 32 * MB);   // over wkh (after M)
  unsigned short* xTh = (unsigned short*)(ws + 160 * MB);  // 8 MB
  unsigned short* x16 = (unsigned short*)(ws + 184 * MB);  // 8 MB
  float* score = (float*)d_out;
  float* out   = (float*)d_out;

  // 1) splits / converts
  split_x3<<<4096, 256, 0, stream>>>((const float4*)x, (ushort4*)xh, (ushort4*)xl,
                                     (ushort4*)x16, 1048576);
  split_plain<<<4096, 256, 0, stream>>>((const float4*)Wq, (ushort4*)wqh, (ushort4*)wql, 1048576);
  split_plain<<<4096, 256, 0, stream>>>((const float4*)Wk, (ushort4*)wkh, (ushort4*)wkl, 1048576);
  split_T<false><<<dim3(N / 32, D / 32), 256, 0, stream>>>(Wv, wvh, nullptr, D, N);  // wvh = Wv^T
  split_T<false><<<dim3(D / 32, N / 32), 256, 0, stream>>>(x, xTh, nullptr, N, D);   // xTh = x^T

  // 2) M = Wq @ Wk^T (1024x1024, K=4096), 3-pass split, 16-way K-split (256 wg)
  gemm_fused3<false><<<dim3(16, 16), 512, 0, stream>>>(
      wqh, 0u, 8 * MEL, 16 * MEL, 24 * MEL,
      1024, 4096, 256, 4, Mpart, (size_t)1024 * 1024);
  // 3) Mt = transpose(sum Mpart) -> split hi/lo bf16
  reduceT_M<<<dim3(32, 32), 256, 0, stream>>>(Mpart, Mth, Mtl, 16);

  // 4) y = x @ Mt^T (4096x1024, K=1024), 3-pass split, 4-way K-split (256 wg)
  gemm_fused3<false><<<dim3(64, 4), 512, 0, stream>>>(
      xh, 0u, 8 * MEL, 56 * MEL, 58 * MEL,
      1024, 1024, 256, 4, ypart, (size_t)4096 * 1024);
  // 5) y16 = f16(sum ypart)
  reduce_f16<<<4096, 256, 0, stream>>>(
      (const float4*)ypart, (ushort4*)y16, 1048576, 4, 1048576);

  // 6) score = y16 @ x16^T (4096x4096, K=1024), single f16 pass -> fp32 d_out
  gemm_plain<true, 1><<<dim3(256, 1), 512, 0, stream>>>(
      y16, x16, N, 1024, 1024, 16, score, 0);

  // 7) p = softmax(score) -> bf16
  softmax_rows<<<N, 256, 0, stream>>>(score, p, N);

  // 8) z = p @ x (4096x1024, K=4096) via B=xT; 4-way K-split -> fp32 partials
  gemm_plain<false, 0><<<dim3(64, 4), 512, 0, stream>>>(
      p, xTh, 1024, 4096, 1024, 4, zpart, (size_t)4096 * 1024);
  // 9) zh = bf16(sum zpart)  (lo term unused downstream)
  reduce_bf16<<<4096, 256, 0, stream>>>(
      (const float4*)zpart, (ushort4*)zh, 1048576, 4, 1048576);

  // 10) out = z @ Wv = zh @ wvh^T (4096x4096, K=1024) -> fp32 d_out
  gemm_plain<true, 0><<<dim3(256, 1), 512, 0, stream>>>(
      zh, wvh, N, 1024, 1024, 16, out, 0);
}